// Round 3
// baseline (2733.942 us; speedup 1.0000x reference)
//
#include <hip/hip_runtime.h>

// EdgeAttrHeteroConv — round 10 (= R9 resubmitted verbatim; rounds 0-2 all
// died on infra before any measurement: 2x GPUAcquisitionTimeout, 1x
// "container failed twice"). Full bounds/alignment/capture audit done —
// kernel cannot plausibly fault. Structure: eliminate R7's 198M global fp32
// atomicAdds (theory: atomic-RMW-bound at 6412 us). Build per-destination CSR
// (counting sort: hist -> 3-kernel scan -> scatter of edge ids; int atomics on
// small counters only), then ONE WAVE PER DESTINATION accumulates the exact
// online-softmax (running-max rescale) in registers and writes agg=num/s once,
// coalesced. Zero atomics in the hot loop.
// Polish kept from R9: float2 gathers/stores in agg_k (hipcc won't
// auto-vectorize), readfirstlane on wave-uniform CSR values.
// Math identical to the R6/R7-verified path (gate table for t0, fused
// shfl-matmul gate for t2, per-head shfl_xor reduce, leakyrelu 0.2).
// Output fp32, protocol identical to R7 (verified there).

typedef unsigned short u16;

__device__ __forceinline__ u16 f2b(float f) {
    if (!(f == f)) f = 0.f;
    union { float f; unsigned int i; } v; v.f = f;
    unsigned int r = v.i + 0x7FFFu + ((v.i >> 16) & 1u);
    return (u16)(r >> 16);
}
__device__ __forceinline__ float b2f(u16 u) {
    union { unsigned int i; float f; } v; v.i = ((unsigned int)u) << 16; return v.f;
}
__device__ __forceinline__ float sigm(float x) { return 1.f / (1.f + expf(-x)); }

// ---------------------------------------------------------------------------
__global__ void zero_k(float* __restrict__ p, int n) {
    int i = blockIdx.x * 256 + threadIdx.x;
    if (i < n) p[i] = 0.f;
}

__global__ void senthost_k(float* out, float v) { out[0] = v; }

// ---------------------------------------------------------------------------
// CSR build: histogram -> 3-kernel exclusive scan (1024-elem chunks) -> scatter
__global__ void hist_k(const int* __restrict__ dst, int* __restrict__ deg, int E, int Nd) {
    int e = blockIdx.x * 256 + threadIdx.x;
    if (e < E) {
        int d = dst[e];
        d = d < 0 ? 0 : (d >= Nd ? Nd - 1 : d);
        atomicAdd(&deg[d], 1);
    }
}

__global__ void scan1_k(const int* __restrict__ deg, int* __restrict__ csum, int Nd) {
    __shared__ int red[256];
    int base = blockIdx.x * 1024;
    int t = threadIdx.x;
    int s = 0;
    for (int i = 0; i < 4; i++) {
        int idx = base + t * 4 + i;
        if (idx < Nd) s += deg[idx];
    }
    red[t] = s;
    __syncthreads();
    for (int off = 128; off > 0; off >>= 1) {
        if (t < off) red[t] += red[t + off];
        __syncthreads();
    }
    if (t == 0) csum[blockIdx.x] = red[0];
}

__global__ void scan2_k(int* __restrict__ csum, int nch) {
    if (threadIdx.x == 0) {
        int acc = 0;
        for (int i = 0; i < nch; i++) { int v = csum[i]; csum[i] = acc; acc += v; }
    }
}

__global__ void scan3_k(const int* __restrict__ deg, const int* __restrict__ csum,
                        int* __restrict__ starts, int* __restrict__ cur, int Nd) {
    __shared__ int sc[256];
    int base = blockIdx.x * 1024;
    int t = threadIdx.x;
    int v[4];
    int s = 0;
    for (int i = 0; i < 4; i++) {
        int idx = base + t * 4 + i;
        v[i] = idx < Nd ? deg[idx] : 0;
        s += v[i];
    }
    sc[t] = s;
    __syncthreads();
    for (int off = 1; off < 256; off <<= 1) {           // Hillis-Steele inclusive
        int add = (t >= off) ? sc[t - off] : 0;
        __syncthreads();
        sc[t] += add;
        __syncthreads();
    }
    int excl = sc[t] - s + csum[blockIdx.x];
    for (int i = 0; i < 4; i++) {
        int idx = base + t * 4 + i;
        if (idx < Nd) { starts[idx] = excl; cur[idx] = excl; excl += v[i]; }
    }
}

__global__ void scatter_k(const int* __restrict__ dst, int* __restrict__ cur,
                          int* __restrict__ perm, int E, int Nd) {
    int e = blockIdx.x * 256 + threadIdx.x;
    if (e < E) {
        int d = dst[e];
        d = d < 0 ? 0 : (d >= Nd ? Nd - 1 : d);
        int p = atomicAdd(&cur[d], 1);
        perm[p] = e;
    }
}

// ---------------------------------------------------------------------------
__global__ void gtbl_k(const float* __restrict__ temb, const float* __restrict__ semb,
                       const float* __restrict__ Wg, const float* __restrict__ bg,
                       float* __restrict__ gtbl) {
    int idx = blockIdx.x * 256 + threadIdx.x;
    if (idx >= 8192) return;
    int combo = idx >> 7, c = idx & 127;
    int a = combo >> 3, b = combo & 7;
    float s = bg[c];
    for (int k = 0; k < 32; k++) s += temb[a * 32 + k] * Wg[k * 128 + c];
    for (int k = 0; k < 32; k++) s += semb[b * 32 + k] * Wg[(32 + k) * 128 + c];
    gtbl[combo * 128 + c] = sigm(s);
}

__global__ void hsrow_k(const float* __restrict__ x, const float* __restrict__ W,
                        const float* __restrict__ bias, float* __restrict__ hs, int N) {
    int tid = threadIdx.x;
    int row = blockIdx.x * 2 + (tid >> 7);
    int c = tid & 127;
    if (row >= N) return;
    float acc = bias[c];
    for (int k = 0; k < 128; k++)
        acc += x[(size_t)row * 128 + k] * W[k * 128 + c];
    hs[(size_t)row * 128 + c] = acc;
}

__global__ void adirect_k(const float* __restrict__ x, const float* __restrict__ Wdst_t,
                          const float* __restrict__ bdst_t, const float* __restrict__ attn_t,
                          float* __restrict__ ad, int N) {
    int lane = threadIdx.x & 63;
    int gw = (blockIdx.x * 256 + threadIdx.x) >> 6;
    int nw = gridDim.x * 4;
    int c0 = 2 * lane, c1 = 2 * lane + 1;
    float aa = attn_t[c0], ab = attn_t[c1];
    for (int j = gw; j < N; j += nw) {
        float ha = bdst_t[c0], hb = bdst_t[c1];
        for (int k = 0; k < 128; k++) {
            float xk = x[(size_t)j * 128 + k];
            ha += xk * Wdst_t[k * 128 + c0];
            hb += xk * Wdst_t[k * 128 + c1];
        }
        float part = ha * aa + hb * ab;
        part += __shfl_xor(part, 1);
        part += __shfl_xor(part, 2);
        part += __shfl_xor(part, 4);
        part += __shfl_xor(part, 8);
        if ((lane & 15) == 0) ad[j * 4 + (lane >> 4)] = part;
    }
}

// ---------------------------------------------------------------------------
// Gather-side aggregation: one wave per destination node. MODE 0: plain.
// MODE 1: categorical gate table (t0). MODE 2: fused continuous gate (t2).
// Exact online softmax (running max m, rescale on new max).
template <int MODE>
__global__ __launch_bounds__(256) void agg_k(const float* __restrict__ hs,
                                             const float* __restrict__ ad,
                                             const int* __restrict__ src,
                                             const int* __restrict__ perm,
                                             const int* __restrict__ starts,
                                             const int* __restrict__ deg,
                                             const float* __restrict__ attn_t,
                                             const int* __restrict__ cg,
                                             const float* __restrict__ gtbl,
                                             const float* __restrict__ cp,
                                             const float* __restrict__ W1c,
                                             const float* __restrict__ b1c,
                                             const float* __restrict__ W2c,
                                             const float* __restrict__ b2c,
                                             float* __restrict__ agg,
                                             int Nd, int Ns) {
    __shared__ u16 w2l[MODE == 2 ? 16384 : 1];
    if (MODE == 2) {
        for (int i = threadIdx.x; i < 16384; i += 256) w2l[i] = f2b(W2c[i]);
        __syncthreads();
    }
    int lane = threadIdx.x & 63;
    int gw = (blockIdx.x * 256 + threadIdx.x) >> 6;
    int nw = gridDim.x * 4;
    int c0 = 2 * lane, c1 = 2 * lane + 1;
    float ax = attn_t[c0], ay = attn_t[c1];
    float w1a = 0.f, w1b = 0.f, w1c_ = 0.f, w1d = 0.f, w1e = 0.f, w1f = 0.f;
    float b1a = 0.f, b1b = 0.f, bc2a = 0.f, bc2b = 0.f;
    if (MODE == 2) {
        w1a = W1c[0 * 128 + c0]; w1b = W1c[1 * 128 + c0]; w1c_ = W1c[2 * 128 + c0];
        w1d = W1c[0 * 128 + c1]; w1e = W1c[1 * 128 + c1]; w1f = W1c[2 * 128 + c1];
        b1a = b1c[c0]; b1b = b1c[c1];
        bc2a = b2c[c0]; bc2b = b2c[c1];
    }
    int h = lane >> 4;
    const float2* hs2v = (const float2*)hs;
    const float2* gt2v = (const float2*)gtbl;
    float2* agg2v = (float2*)agg;
    for (int j = gw; j < Nd; j += nw) {
        int st = __builtin_amdgcn_readfirstlane(starts[j]);
        int n  = __builtin_amdgcn_readfirstlane(deg[j]);
        float adv = ad[j * 4 + h];
        float m = -3.0e38f, s = 0.f, num0 = 0.f, num1 = 0.f;
        for (int q = 0; q < n; q++) {
            int e = __builtin_amdgcn_readfirstlane(perm[st + q]);
            int si = __builtin_amdgcn_readfirstlane(src[e]);
            si = si < 0 ? 0 : (si >= Ns ? Ns - 1 : si);
            float2 hv = hs2v[(size_t)si * 64 + lane];
            float mx = hv.x, my = hv.y;
            if (MODE == 1) {
                int a = cg[2 * e] & 7, b = cg[2 * e + 1] & 7;
                float2 gv = gt2v[(a * 8 + b) * 64 + lane];
                mx *= gv.x;
                my *= gv.y;
            } else if (MODE == 2) {
                float p0 = cp[(size_t)e * 3 + 0];
                float p1 = cp[(size_t)e * 3 + 1];
                float p2 = cp[(size_t)e * 3 + 2];
                float z0 = b1a + p0 * w1a + p1 * w1b + p2 * w1c_;
                float z1 = b1b + p0 * w1d + p1 * w1e + p2 * w1f;
                float u0 = 0.5f * z0 * (1.f + erff(z0 * 0.70710678118654752f));
                float u1 = 0.5f * z1 * (1.f + erff(z1 * 0.70710678118654752f));
                float acc0 = bc2a, acc1 = bc2b;
                for (int kk = 0; kk < 64; kk++) {
                    float ua = __shfl(u0, kk);
                    float ub = __shfl(u1, kk);
                    acc0 += ua * b2f(w2l[(2 * kk) * 128 + c0]) + ub * b2f(w2l[(2 * kk + 1) * 128 + c0]);
                    acc1 += ua * b2f(w2l[(2 * kk) * 128 + c1]) + ub * b2f(w2l[(2 * kk + 1) * 128 + c1]);
                }
                mx *= sigm(acc0);
                my *= sigm(acc1);
            }
            float p = mx * ax + my * ay;
            p += __shfl_xor(p, 1);
            p += __shfl_xor(p, 2);
            p += __shfl_xor(p, 4);
            p += __shfl_xor(p, 8);
            float logit = p + adv;
            logit = logit > 0.f ? logit : 0.2f * logit;
            if (logit > m) {                 // online-softmax rescale (exact)
                float r = expf(m - logit);   // m==-3e38 -> r==0 on first edge
                s *= r; num0 *= r; num1 *= r;
                m = logit;
            }
            float ex = expf(logit - m);
            s += ex;
            num0 += ex * mx;
            num1 += ex * my;
        }
        float inv = s > 0.f ? 1.f / s : 0.f;
        float2 o; o.x = num0 * inv; o.y = num1 * inv;
        agg2v[(size_t)j * 64 + lane] = o;
    }
}

// out[row][c] = bo[c] + sum_k (aggA+aggB)(row,k) * Wo[k][c] ; fp32 output
__global__ void outrow_k(const float* __restrict__ aggA, const float* __restrict__ aggB,
                         const float* __restrict__ Wo, const float* __restrict__ bo,
                         float* __restrict__ out, int N) {
    int tid = threadIdx.x;
    int row = blockIdx.x * 2 + (tid >> 7);
    int c = tid & 127;
    if (row >= N) return;
    float acc = bo[c];
    for (int k = 0; k < 128; k++) {
        float a = aggA ? aggA[(size_t)row * 128 + k] : 0.f;
        if (aggB) a += aggB[(size_t)row * 128 + k];
        acc += a * Wo[k * 128 + c];
    }
    out[(size_t)row * 128 + c] = acc;
}

// ---------------------------------------------------------------------------
extern "C" void kernel_launch(void* const* d_in, const int* in_sizes, int n_in,
                              void* d_out, int out_size, void* d_ws, size_t ws_size,
                              hipStream_t stream) {
    static const int expect[29] = {
        6400000, 3840000, 1280000, 640000,
        500000, 500000, 500000, 500000, 250000, 250000, 250000, 250000,
        1000000, 750000, 65536, 512, 65536, 512, 512, 320, 256,
        8192, 128, 384, 128, 16384, 128, 65536, 512};
    int bad = 0;
    if (n_in != 29) bad = 1;
    else {
        for (int i = 0; i < 29; i++)
            if (in_sizes[i] != expect[i]) { bad = 4 + i; break; }
    }
    if (!bad && out_size != 12160000) bad = 2;
    if (!bad && ws_size < (size_t)63425536) bad = 3;
    if (bad) {
        senthost_k<<<1, 1, 0, stream>>>((float*)d_out, 4096.f * (float)bad);
        return;
    }

    const float* x_chem = (const float*)d_in[0];
    const float* x_gene = (const float*)d_in[1];
    const float* x_dis  = (const float*)d_in[2];
    const float* x_path = (const float*)d_in[3];
    const int* src0 = (const int*)d_in[4];  const int* dst0 = (const int*)d_in[5];
    const int* src1 = (const int*)d_in[6];  const int* dst1 = (const int*)d_in[7];
    const int* src2 = (const int*)d_in[8];  const int* dst2 = (const int*)d_in[9];
    const int* src3 = (const int*)d_in[10]; const int* dst3 = (const int*)d_in[11];
    const int*   cg   = (const int*)d_in[12];
    const float* cp   = (const float*)d_in[13];
    const float* Wsrc = (const float*)d_in[14]; const float* bsrc = (const float*)d_in[15];
    const float* Wdst = (const float*)d_in[16]; const float* bdst = (const float*)d_in[17];
    const float* attn = (const float*)d_in[18];
    const float* temb = (const float*)d_in[19]; const float* semb = (const float*)d_in[20];
    const float* Wg   = (const float*)d_in[21]; const float* bg   = (const float*)d_in[22];
    const float* W1c  = (const float*)d_in[23]; const float* b1c  = (const float*)d_in[24];
    const float* W2c  = (const float*)d_in[25]; const float* b2c  = (const float*)d_in[26];
    const float* Wout = (const float*)d_in[27]; const float* bout = (const float*)d_in[28];

    constexpr int NC = 50000, NG = 30000, ND = 10000, NP = 5000;
    constexpr int E0 = 500000, E1 = 500000, E2 = 250000, E3 = 250000;

    char* ws = (char*)d_ws;
    float* gt   = (float*)ws;              // [64][128] f32 = 32768 B
    int*   csum = (int*)(ws + 32768);      // chunk sums for scan (<=49 ints)
    char*  A    = ws + 65536;              // stage arena (<= 63,360,000 B)

    float* out = (float*)d_out;
    float* out_chem = out;
    float* out_gene = out + (size_t)NC * 128;
    float* out_dis  = out + (size_t)(NC + NG) * 128;
    float* out_path = out + (size_t)(NC + NG + ND) * 128;

    gtbl_k<<<32, 256, 0, stream>>>(temb, semb, Wg, bg, gt);

    // ---------- STAGE A: chemical output (t1: gene -> chemical) ----------
    {
        float* hs1  = (float*)(A);                 // 15,360,000
        float* ad1  = (float*)(A + 15360000);      //    800,000
        int*   deg  = (int*)  (A + 16160000);      //    200,000
        int*   sts  = (int*)  (A + 16360000);      //    200,000
        int*   cur  = (int*)  (A + 16560000);      //    200,000
        int*   perm = (int*)  (A + 16760000);      //  2,000,000
        float* agg1 = (float*)(A + 18760000);      // 25,600,000 (ends 44,360,000)
        int nch = (NC + 1023) / 1024;
        zero_k<<<(NC + 255) / 256, 256, 0, stream>>>((float*)deg, NC);
        hist_k<<<(E1 + 255) / 256, 256, 0, stream>>>(dst1, deg, E1, NC);
        scan1_k<<<nch, 256, 0, stream>>>(deg, csum, NC);
        scan2_k<<<1, 64, 0, stream>>>(csum, nch);
        scan3_k<<<nch, 256, 0, stream>>>(deg, csum, sts, cur, NC);
        scatter_k<<<(E1 + 255) / 256, 256, 0, stream>>>(dst1, cur, perm, E1, NC);
        hsrow_k<<<(NG + 1) / 2, 256, 0, stream>>>(x_gene, Wsrc + 1 * 16384, bsrc + 1 * 128, hs1, NG);
        adirect_k<<<1024, 256, 0, stream>>>(x_chem, Wdst + 1 * 16384, bdst + 1 * 128, attn + 1 * 128, ad1, NC);
        agg_k<0><<<2048, 256, 0, stream>>>(hs1, ad1, src1, perm, sts, deg, attn + 1 * 128,
                                           nullptr, nullptr, nullptr, nullptr, nullptr, nullptr, nullptr,
                                           agg1, NC, NG);
        outrow_k<<<(NC + 1) / 2, 256, 0, stream>>>(agg1, nullptr,
                                                   Wout + 0 * 16384, bout + 0 * 128, out_chem, NC);
    }

    // ---------- STAGE B: pathway output (t2: chemical -> pathway) ----------
    {
        float* hs2  = (float*)(A);                 // 25,600,000
        float* ad2  = (float*)(A + 25600000);      //     80,000
        int*   deg  = (int*)  (A + 25680000);      //     20,000
        int*   sts  = (int*)  (A + 25700000);      //     20,000
        int*   cur  = (int*)  (A + 25720000);      //     20,000
        int*   perm = (int*)  (A + 25740000);      //  1,000,000
        float* agg2 = (float*)(A + 26740000);      //  2,560,000 (ends 29,300,000)
        int nch = (NP + 1023) / 1024;
        zero_k<<<(NP + 255) / 256, 256, 0, stream>>>((float*)deg, NP);
        hist_k<<<(E2 + 255) / 256, 256, 0, stream>>>(dst2, deg, E2, NP);
        scan1_k<<<nch, 256, 0, stream>>>(deg, csum, NP);
        scan2_k<<<1, 64, 0, stream>>>(csum, nch);
        scan3_k<<<nch, 256, 0, stream>>>(deg, csum, sts, cur, NP);
        scatter_k<<<(E2 + 255) / 256, 256, 0, stream>>>(dst2, cur, perm, E2, NP);
        hsrow_k<<<(NC + 1) / 2, 256, 0, stream>>>(x_chem, Wsrc + 2 * 16384, bsrc + 2 * 128, hs2, NC);
        adirect_k<<<512, 256, 0, stream>>>(x_path, Wdst + 2 * 16384, bdst + 2 * 128, attn + 2 * 128, ad2, NP);
        agg_k<2><<<1250, 256, 0, stream>>>(hs2, ad2, src2, perm, sts, deg, attn + 2 * 128,
                                           nullptr, nullptr, cp, W1c, b1c, W2c, b2c,
                                           agg2, NP, NC);
        outrow_k<<<(NP + 1) / 2, 256, 0, stream>>>(agg2, nullptr,
                                                   Wout + 3 * 16384, bout + 3 * 128, out_path, NP);
    }

    // ---------- STAGE C: gene output (t0 + t3, sequential buffer reuse) -----
    {
        float* agg0 = (float*)(A + 32000000);      // 15,360,000 (ends 47,360,000)
        float* agg3 = (float*)(A + 47360000);      // 15,360,000 (ends 62,720,000)
        float* ad0  = (float*)(A + 25600000);      //    480,000
        float* ad3  = (float*)(A + 28440000);      //    480,000 (survives phase 2)
        int*   deg  = (int*)  (A + 26080000);      //    120,000
        int*   sts  = (int*)  (A + 26200000);      //    120,000
        int*   cur  = (int*)  (A + 26320000);      //    120,000
        int*   perm = (int*)  (A + 26440000);      //  2,000,000 (ends 28,440,000)
        int nch = (NG + 1023) / 1024;

        // phase 1: t0 chemical -> gene (categorical gate)
        float* hs0 = (float*)(A);                  // 25,600,000
        zero_k<<<(NG + 255) / 256, 256, 0, stream>>>((float*)deg, NG);
        hist_k<<<(E0 + 255) / 256, 256, 0, stream>>>(dst0, deg, E0, NG);
        scan1_k<<<nch, 256, 0, stream>>>(deg, csum, NG);
        scan2_k<<<1, 64, 0, stream>>>(csum, nch);
        scan3_k<<<nch, 256, 0, stream>>>(deg, csum, sts, cur, NG);
        scatter_k<<<(E0 + 255) / 256, 256, 0, stream>>>(dst0, cur, perm, E0, NG);
        hsrow_k<<<(NC + 1) / 2, 256, 0, stream>>>(x_chem, Wsrc + 0 * 16384, bsrc + 0 * 128, hs0, NC);
        adirect_k<<<1024, 256, 0, stream>>>(x_gene, Wdst + 0 * 16384, bdst + 0 * 128, attn + 0 * 128, ad0, NG);
        adirect_k<<<1024, 256, 0, stream>>>(x_gene, Wdst + 3 * 16384, bdst + 3 * 128, attn + 3 * 128, ad3, NG);
        agg_k<1><<<2048, 256, 0, stream>>>(hs0, ad0, src0, perm, sts, deg, attn + 0 * 128,
                                           cg, gt, nullptr, nullptr, nullptr, nullptr, nullptr,
                                           agg0, NG, NC);

        // phase 2: t3 disease -> gene (plain), reusing hs/CSR buffers
        float* hs3 = (float*)(A);                  //  5,120,000
        zero_k<<<(NG + 255) / 256, 256, 0, stream>>>((float*)deg, NG);
        hist_k<<<(E3 + 255) / 256, 256, 0, stream>>>(dst3, deg, E3, NG);
        scan1_k<<<nch, 256, 0, stream>>>(deg, csum, NG);
        scan2_k<<<1, 64, 0, stream>>>(csum, nch);
        scan3_k<<<nch, 256, 0, stream>>>(deg, csum, sts, cur, NG);
        scatter_k<<<(E3 + 255) / 256, 256, 0, stream>>>(dst3, cur, perm, E3, NG);
        hsrow_k<<<(ND + 1) / 2, 256, 0, stream>>>(x_dis, Wsrc + 3 * 16384, bsrc + 3 * 128, hs3, ND);
        agg_k<0><<<2048, 256, 0, stream>>>(hs3, ad3, src3, perm, sts, deg, attn + 3 * 128,
                                           nullptr, nullptr, nullptr, nullptr, nullptr, nullptr, nullptr,
                                           agg3, NG, ND);
        outrow_k<<<(NG + 1) / 2, 256, 0, stream>>>(agg0, agg3,
                                                   Wout + 1 * 16384, bout + 1 * 128, out_gene, NG);
    }

    // ---------- STAGE D: disease output (no incoming edges: bias only) ------
    outrow_k<<<(ND + 1) / 2, 256, 0, stream>>>(nullptr, nullptr,
                                               Wout + 2 * 16384, bout + 2 * 128, out_dis, ND);
}

// Round 4
// 1839.496 us; speedup vs baseline: 1.4862x; 1.4862x over previous
//
#include <hip/hip_runtime.h>

// EdgeAttrHeteroConv — round 11. R10 measured 2734 us; top dispatch is
// agg_k<2> (t2 gate, LDS 32768) at 675 us — LDS-pipe-bound: 384 DS wave-ops
// per edge (64-iter shfl+bf16-LDS gate matmul). Fix A: precompute the t2 gate
// per edge in PERM ORDER (contiguous per destination), in 4 destination
// chunks (f16 storage, 20.5 MB buffer, CAP 80000 edges/chunk >> expected
// 62.5K). gate_k holds the W2 column for its channel in 64 packed-f16x2
// VGPRs and runs v_dot2_f32_f16 against an LDS-staged u vector: 34 DS-ops
// per edge instead of 384. agg MODE 3 then just loads a coalesced f16x2 gate.
// Fix B: dense kernels (hsrow/adirect/outrow) restructured to 4 rows/wave x
// 2 ch/lane with float4 x-loads + float2 W-loads (was 1 ch/thread, 2 scalar
// loads per FMA) — ~4x fewer load instrs per FMA, 4x W reuse.
// Everything else identical to the R10-verified pipeline (CSR counting sort,
// wave-per-destination exact online softmax, zero atomics in hot loops).
// Output fp32; protocol identical (verified R10, absmax 1.95e-3).

typedef unsigned short u16;
typedef _Float16 h2_t __attribute__((ext_vector_type(2)));
union H2U { unsigned u; h2_t h; };
union HSU { _Float16 f; unsigned short s; };

#if __has_builtin(__builtin_amdgcn_fdot2)
#define FDOT2(a, b, c) __builtin_amdgcn_fdot2((a), (b), (c), false)
#else
#define FDOT2(a, b, c) ((c) + (float)(a).x * (float)(b).x + (float)(a).y * (float)(b).y)
#endif

__device__ __forceinline__ float sigm(float x) { return 1.f / (1.f + expf(-x)); }

// ---------------------------------------------------------------------------
__global__ void zero_k(float* __restrict__ p, int n) {
    int i = blockIdx.x * 256 + threadIdx.x;
    if (i < n) p[i] = 0.f;
}

__global__ void senthost_k(float* out, float v) { out[0] = v; }

// ---------------------------------------------------------------------------
// CSR build: histogram -> 3-kernel exclusive scan (1024-elem chunks) -> scatter
__global__ void hist_k(const int* __restrict__ dst, int* __restrict__ deg, int E, int Nd) {
    int e = blockIdx.x * 256 + threadIdx.x;
    if (e < E) {
        int d = dst[e];
        d = d < 0 ? 0 : (d >= Nd ? Nd - 1 : d);
        atomicAdd(&deg[d], 1);
    }
}

__global__ void scan1_k(const int* __restrict__ deg, int* __restrict__ csum, int Nd) {
    __shared__ int red[256];
    int base = blockIdx.x * 1024;
    int t = threadIdx.x;
    int s = 0;
    for (int i = 0; i < 4; i++) {
        int idx = base + t * 4 + i;
        if (idx < Nd) s += deg[idx];
    }
    red[t] = s;
    __syncthreads();
    for (int off = 128; off > 0; off >>= 1) {
        if (t < off) red[t] += red[t + off];
        __syncthreads();
    }
    if (t == 0) csum[blockIdx.x] = red[0];
}

__global__ void scan2_k(int* __restrict__ csum, int nch) {
    if (threadIdx.x == 0) {
        int acc = 0;
        for (int i = 0; i < nch; i++) { int v = csum[i]; csum[i] = acc; acc += v; }
    }
}

__global__ void scan3_k(const int* __restrict__ deg, const int* __restrict__ csum,
                        int* __restrict__ starts, int* __restrict__ cur, int Nd) {
    __shared__ int sc[256];
    int base = blockIdx.x * 1024;
    int t = threadIdx.x;
    int v[4];
    int s = 0;
    for (int i = 0; i < 4; i++) {
        int idx = base + t * 4 + i;
        v[i] = idx < Nd ? deg[idx] : 0;
        s += v[i];
    }
    sc[t] = s;
    __syncthreads();
    for (int off = 1; off < 256; off <<= 1) {           // Hillis-Steele inclusive
        int add = (t >= off) ? sc[t - off] : 0;
        __syncthreads();
        sc[t] += add;
        __syncthreads();
    }
    int excl = sc[t] - s + csum[blockIdx.x];
    for (int i = 0; i < 4; i++) {
        int idx = base + t * 4 + i;
        if (idx < Nd) { starts[idx] = excl; cur[idx] = excl; excl += v[i]; }
    }
}

__global__ void scatter_k(const int* __restrict__ dst, int* __restrict__ cur,
                          int* __restrict__ perm, int E, int Nd) {
    int e = blockIdx.x * 256 + threadIdx.x;
    if (e < E) {
        int d = dst[e];
        d = d < 0 ? 0 : (d >= Nd ? Nd - 1 : d);
        int p = atomicAdd(&cur[d], 1);
        perm[p] = e;
    }
}

// ---------------------------------------------------------------------------
__global__ void gtbl_k(const float* __restrict__ temb, const float* __restrict__ semb,
                       const float* __restrict__ Wg, const float* __restrict__ bg,
                       float* __restrict__ gtbl) {
    int idx = blockIdx.x * 256 + threadIdx.x;
    if (idx >= 8192) return;
    int combo = idx >> 7, c = idx & 127;
    int a = combo >> 3, b = combo & 7;
    float s = bg[c];
    for (int k = 0; k < 32; k++) s += temb[a * 32 + k] * Wg[k * 128 + c];
    for (int k = 0; k < 32; k++) s += semb[b * 32 + k] * Wg[(32 + k) * 128 + c];
    gtbl[combo * 128 + c] = sigm(s);
}

// ---------------------------------------------------------------------------
// Dense kernels: 4 rows per wave, 2 channels per lane, float4 x / float2 W.
#define STEP4(A, XV)                                     \
    A.x += XV.x * w0.x; A.y += XV.x * w0.y;              \
    A.x += XV.y * w1.x; A.y += XV.y * w1.y;              \
    A.x += XV.z * w2.x; A.y += XV.z * w2.y;              \
    A.x += XV.w * w3.x; A.y += XV.w * w3.y;

__global__ __launch_bounds__(256) void hsrow4_k(const float* __restrict__ x, const float* __restrict__ W,
                                                const float* __restrict__ bias, float* __restrict__ hs, int N) {
    int l = threadIdx.x & 63;
    int wv = (blockIdx.x * 256 + threadIdx.x) >> 6;
    int r0 = wv * 4;
    if (r0 >= N) return;
    int c0 = 2 * l;
    float2 bi = *(const float2*)&bias[c0];
    float2 a0 = bi, a1 = bi, a2 = bi, a3 = bi;
    const float4* x4 = (const float4*)x;
    const float2* Wv = (const float2*)W;
    int r1 = min(r0 + 1, N - 1), r2 = min(r0 + 2, N - 1), r3 = min(r0 + 3, N - 1);
    #pragma unroll 4
    for (int kb = 0; kb < 32; kb++) {
        float4 xv0 = x4[(size_t)r0 * 32 + kb];
        float4 xv1 = x4[(size_t)r1 * 32 + kb];
        float4 xv2 = x4[(size_t)r2 * 32 + kb];
        float4 xv3 = x4[(size_t)r3 * 32 + kb];
        float2 w0 = Wv[(4 * kb + 0) * 64 + l];
        float2 w1 = Wv[(4 * kb + 1) * 64 + l];
        float2 w2 = Wv[(4 * kb + 2) * 64 + l];
        float2 w3 = Wv[(4 * kb + 3) * 64 + l];
        STEP4(a0, xv0) STEP4(a1, xv1) STEP4(a2, xv2) STEP4(a3, xv3)
    }
    float2* o = (float2*)hs;
    o[(size_t)r0 * 64 + l] = a0;
    if (r0 + 1 < N) o[(size_t)(r0 + 1) * 64 + l] = a1;
    if (r0 + 2 < N) o[(size_t)(r0 + 2) * 64 + l] = a2;
    if (r0 + 3 < N) o[(size_t)(r0 + 3) * 64 + l] = a3;
}

__global__ __launch_bounds__(256) void adirect4_k(const float* __restrict__ x, const float* __restrict__ Wd,
                                                  const float* __restrict__ bd, const float* __restrict__ attn_t,
                                                  float* __restrict__ ad, int N) {
    int l = threadIdx.x & 63;
    int wv = (blockIdx.x * 256 + threadIdx.x) >> 6;
    int r0 = wv * 4;
    if (r0 >= N) return;
    int c0 = 2 * l;
    float2 bi = *(const float2*)&bd[c0];
    float2 a0 = bi, a1 = bi, a2 = bi, a3 = bi;
    const float4* x4 = (const float4*)x;
    const float2* Wv = (const float2*)Wd;
    int r1 = min(r0 + 1, N - 1), r2 = min(r0 + 2, N - 1), r3 = min(r0 + 3, N - 1);
    #pragma unroll 4
    for (int kb = 0; kb < 32; kb++) {
        float4 xv0 = x4[(size_t)r0 * 32 + kb];
        float4 xv1 = x4[(size_t)r1 * 32 + kb];
        float4 xv2 = x4[(size_t)r2 * 32 + kb];
        float4 xv3 = x4[(size_t)r3 * 32 + kb];
        float2 w0 = Wv[(4 * kb + 0) * 64 + l];
        float2 w1 = Wv[(4 * kb + 1) * 64 + l];
        float2 w2 = Wv[(4 * kb + 2) * 64 + l];
        float2 w3 = Wv[(4 * kb + 3) * 64 + l];
        STEP4(a0, xv0) STEP4(a1, xv1) STEP4(a2, xv2) STEP4(a3, xv3)
    }
    float2 at = *(const float2*)&attn_t[c0];
    int h = l >> 4;
    float t0 = a0.x * at.x + a0.y * at.y;
    float t1 = a1.x * at.x + a1.y * at.y;
    float t2 = a2.x * at.x + a2.y * at.y;
    float t3 = a3.x * at.x + a3.y * at.y;
    t0 += __shfl_xor(t0, 1); t0 += __shfl_xor(t0, 2); t0 += __shfl_xor(t0, 4); t0 += __shfl_xor(t0, 8);
    t1 += __shfl_xor(t1, 1); t1 += __shfl_xor(t1, 2); t1 += __shfl_xor(t1, 4); t1 += __shfl_xor(t1, 8);
    t2 += __shfl_xor(t2, 1); t2 += __shfl_xor(t2, 2); t2 += __shfl_xor(t2, 4); t2 += __shfl_xor(t2, 8);
    t3 += __shfl_xor(t3, 1); t3 += __shfl_xor(t3, 2); t3 += __shfl_xor(t3, 4); t3 += __shfl_xor(t3, 8);
    if ((l & 15) == 0) {
        ad[(size_t)r0 * 4 + h] = t0;
        if (r0 + 1 < N) ad[(size_t)(r0 + 1) * 4 + h] = t1;
        if (r0 + 2 < N) ad[(size_t)(r0 + 2) * 4 + h] = t2;
        if (r0 + 3 < N) ad[(size_t)(r0 + 3) * 4 + h] = t3;
    }
}

// NIN = number of agg inputs (0: bias only, 1: A, 2: A+B)
template <int NIN>
__global__ __launch_bounds__(256) void outrow4_k(const float* __restrict__ A, const float* __restrict__ B,
                                                 const float* __restrict__ Wo, const float* __restrict__ bo,
                                                 float* __restrict__ out, int N) {
    int l = threadIdx.x & 63;
    int wv = (blockIdx.x * 256 + threadIdx.x) >> 6;
    int r0 = wv * 4;
    if (r0 >= N) return;
    int c0 = 2 * l;
    float2 bi = *(const float2*)&bo[c0];
    float2* o = (float2*)out;
    if (NIN == 0) {
        o[(size_t)r0 * 64 + l] = bi;
        if (r0 + 1 < N) o[(size_t)(r0 + 1) * 64 + l] = bi;
        if (r0 + 2 < N) o[(size_t)(r0 + 2) * 64 + l] = bi;
        if (r0 + 3 < N) o[(size_t)(r0 + 3) * 64 + l] = bi;
        return;
    }
    float2 a0 = bi, a1 = bi, a2 = bi, a3 = bi;
    const float4* A4 = (const float4*)A;
    const float4* B4 = (const float4*)B;
    const float2* Wv = (const float2*)Wo;
    int r1 = min(r0 + 1, N - 1), r2 = min(r0 + 2, N - 1), r3 = min(r0 + 3, N - 1);
    #pragma unroll 4
    for (int kb = 0; kb < 32; kb++) {
        float4 xv0 = A4[(size_t)r0 * 32 + kb];
        float4 xv1 = A4[(size_t)r1 * 32 + kb];
        float4 xv2 = A4[(size_t)r2 * 32 + kb];
        float4 xv3 = A4[(size_t)r3 * 32 + kb];
        if (NIN == 2) {
            float4 y0 = B4[(size_t)r0 * 32 + kb];
            float4 y1 = B4[(size_t)r1 * 32 + kb];
            float4 y2 = B4[(size_t)r2 * 32 + kb];
            float4 y3 = B4[(size_t)r3 * 32 + kb];
            xv0.x += y0.x; xv0.y += y0.y; xv0.z += y0.z; xv0.w += y0.w;
            xv1.x += y1.x; xv1.y += y1.y; xv1.z += y1.z; xv1.w += y1.w;
            xv2.x += y2.x; xv2.y += y2.y; xv2.z += y2.z; xv2.w += y2.w;
            xv3.x += y3.x; xv3.y += y3.y; xv3.z += y3.z; xv3.w += y3.w;
        }
        float2 w0 = Wv[(4 * kb + 0) * 64 + l];
        float2 w1 = Wv[(4 * kb + 1) * 64 + l];
        float2 w2 = Wv[(4 * kb + 2) * 64 + l];
        float2 w3 = Wv[(4 * kb + 3) * 64 + l];
        STEP4(a0, xv0) STEP4(a1, xv1) STEP4(a2, xv2) STEP4(a3, xv3)
    }
    o[(size_t)r0 * 64 + l] = a0;
    if (r0 + 1 < N) o[(size_t)(r0 + 1) * 64 + l] = a1;
    if (r0 + 2 < N) o[(size_t)(r0 + 2) * 64 + l] = a2;
    if (r0 + 3 < N) o[(size_t)(r0 + 3) * 64 + l] = a3;
}

// ---------------------------------------------------------------------------
// t2 gate precompute, perm-order chunk [starts[j0], starts[j1]).
// One channel per thread; W2 column in 64 packed f16x2 VGPRs; u staged in LDS.
__global__ __launch_bounds__(256) void gate_k(const float* __restrict__ cp,
                                              const float* __restrict__ W1c, const float* __restrict__ b1c,
                                              const float* __restrict__ W2c, const float* __restrict__ b2c,
                                              const int* __restrict__ perm, const int* __restrict__ starts,
                                              u16* __restrict__ gate,
                                              int j0, int j1, int NP_, int E, int CAP) {
    __shared__ __align__(16) u16 u_sh[256];
    int c = threadIdx.x & 127;
    int slot = threadIdx.x >> 7;
    int q0 = starts[j0];
    int q1 = (j1 >= NP_) ? E : starts[j1];
    int npairs = (q1 - q0 + 1) >> 1;
    h2_t w2r[64];
    #pragma unroll
    for (int kk = 0; kk < 64; kk++) {
        h2_t w;
        w.x = (_Float16)W2c[(2 * kk) * 128 + c];
        w.y = (_Float16)W2c[(2 * kk + 1) * 128 + c];
        w2r[kk] = w;
    }
    float w1a = W1c[c], w1b = W1c[128 + c], w1cc = W1c[256 + c];
    float b1 = b1c[c], b2 = b2c[c];
    const uint4* u4 = (const uint4*)u_sh;
    for (int it = blockIdx.x; it < npairs; it += gridDim.x) {
        int q = q0 + it * 2 + slot;
        bool act = q < q1;
        if (act) {
            int e = __builtin_amdgcn_readfirstlane(perm[q]);
            float p0 = cp[(size_t)e * 3 + 0];
            float p1 = cp[(size_t)e * 3 + 1];
            float p2 = cp[(size_t)e * 3 + 2];
            float z = b1 + p0 * w1a + p1 * w1b + p2 * w1cc;
            float u = 0.5f * z * (1.f + erff(z * 0.70710678118654752f));
            HSU cv; cv.f = (_Float16)u;
            u_sh[slot * 128 + c] = cv.s;
        }
        __syncthreads();
        if (act) {
            float acc = b2;
            #pragma unroll
            for (int t = 0; t < 16; t++) {
                uint4 uv = u4[slot * 16 + t];
                H2U x0, x1, x2, x3;
                x0.u = uv.x; x1.u = uv.y; x2.u = uv.z; x3.u = uv.w;
                acc = FDOT2(x0.h, w2r[4 * t + 0], acc);
                acc = FDOT2(x1.h, w2r[4 * t + 1], acc);
                acc = FDOT2(x2.h, w2r[4 * t + 2], acc);
                acc = FDOT2(x3.h, w2r[4 * t + 3], acc);
            }
            float g = sigm(acc);
            int qrel = q - q0;
            if (qrel < CAP) {
                HSU cv2; cv2.f = (_Float16)g;
                gate[(size_t)qrel * 128 + c] = cv2.s;
            }
        }
        __syncthreads();
    }
}

// ---------------------------------------------------------------------------
// Gather-side aggregation: one wave per destination node. MODE 0: plain.
// MODE 1: categorical gate table (t0). MODE 3: precomputed f16 gate (t2).
// Exact online softmax (running max m, rescale on new max).
template <int MODE>
__global__ __launch_bounds__(256) void agg_k(const float* __restrict__ hs,
                                             const float* __restrict__ ad,
                                             const int* __restrict__ src,
                                             const int* __restrict__ perm,
                                             const int* __restrict__ starts,
                                             const int* __restrict__ deg,
                                             const float* __restrict__ attn_t,
                                             const int* __restrict__ cg,
                                             const float* __restrict__ gtbl,
                                             const u16* __restrict__ gate,
                                             float* __restrict__ agg,
                                             int j0, int j1, int Ns) {
    int lane = threadIdx.x & 63;
    int gw = (blockIdx.x * 256 + threadIdx.x) >> 6;
    int nw = gridDim.x * 4;
    int c0 = 2 * lane, c1 = c0 + 1;
    float ax = attn_t[c0], ay = attn_t[c1];
    int h = lane >> 4;
    const float2* hs2v = (const float2*)hs;
    const float2* gt2v = (const float2*)gtbl;
    const unsigned* g32 = (const unsigned*)gate;
    float2* agg2v = (float2*)agg;
    int q0base = 0;
    if (MODE == 3) q0base = __builtin_amdgcn_readfirstlane(starts[j0]);
    for (int j = j0 + gw; j < j1; j += nw) {
        int st = __builtin_amdgcn_readfirstlane(starts[j]);
        int n  = __builtin_amdgcn_readfirstlane(deg[j]);
        float adv = ad[(size_t)j * 4 + h];
        float m = -3.0e38f, s = 0.f, num0 = 0.f, num1 = 0.f;
        for (int q = 0; q < n; q++) {
            int e = __builtin_amdgcn_readfirstlane(perm[st + q]);
            int si = __builtin_amdgcn_readfirstlane(src[e]);
            si = si < 0 ? 0 : (si >= Ns ? Ns - 1 : si);
            float2 hv = hs2v[(size_t)si * 64 + lane];
            float mx = hv.x, my = hv.y;
            if (MODE == 1) {
                int a = cg[2 * e] & 7, b = cg[2 * e + 1] & 7;
                float2 gv = gt2v[(a * 8 + b) * 64 + lane];
                mx *= gv.x;
                my *= gv.y;
            } else if (MODE == 3) {
                int qq = st + q - q0base;
                qq = qq < 79999 ? qq : 79999;
                H2U gu; gu.u = g32[(size_t)qq * 64 + lane];
                mx *= (float)gu.h.x;
                my *= (float)gu.h.y;
            }
            float p = mx * ax + my * ay;
            p += __shfl_xor(p, 1);
            p += __shfl_xor(p, 2);
            p += __shfl_xor(p, 4);
            p += __shfl_xor(p, 8);
            float logit = p + adv;
            logit = logit > 0.f ? logit : 0.2f * logit;
            if (logit > m) {                 // online-softmax rescale (exact)
                float r = expf(m - logit);   // m==-3e38 -> r==0 on first edge
                s *= r; num0 *= r; num1 *= r;
                m = logit;
            }
            float ex = expf(logit - m);
            s += ex;
            num0 += ex * mx;
            num1 += ex * my;
        }
        float inv = s > 0.f ? 1.f / s : 0.f;
        float2 o; o.x = num0 * inv; o.y = num1 * inv;
        agg2v[(size_t)j * 64 + lane] = o;
    }
}

// ---------------------------------------------------------------------------
extern "C" void kernel_launch(void* const* d_in, const int* in_sizes, int n_in,
                              void* d_out, int out_size, void* d_ws, size_t ws_size,
                              hipStream_t stream) {
    static const int expect[29] = {
        6400000, 3840000, 1280000, 640000,
        500000, 500000, 500000, 500000, 250000, 250000, 250000, 250000,
        1000000, 750000, 65536, 512, 65536, 512, 512, 320, 256,
        8192, 128, 384, 128, 16384, 128, 65536, 512};
    int bad = 0;
    if (n_in != 29) bad = 1;
    else {
        for (int i = 0; i < 29; i++)
            if (in_sizes[i] != expect[i]) { bad = 4 + i; break; }
    }
    if (!bad && out_size != 12160000) bad = 2;
    if (!bad && ws_size < (size_t)63425536) bad = 3;
    if (bad) {
        senthost_k<<<1, 1, 0, stream>>>((float*)d_out, 4096.f * (float)bad);
        return;
    }

    const float* x_chem = (const float*)d_in[0];
    const float* x_gene = (const float*)d_in[1];
    const float* x_dis  = (const float*)d_in[2];
    const float* x_path = (const float*)d_in[3];
    const int* src0 = (const int*)d_in[4];  const int* dst0 = (const int*)d_in[5];
    const int* src1 = (const int*)d_in[6];  const int* dst1 = (const int*)d_in[7];
    const int* src2 = (const int*)d_in[8];  const int* dst2 = (const int*)d_in[9];
    const int* src3 = (const int*)d_in[10]; const int* dst3 = (const int*)d_in[11];
    const int*   cg   = (const int*)d_in[12];
    const float* cp   = (const float*)d_in[13];
    const float* Wsrc = (const float*)d_in[14]; const float* bsrc = (const float*)d_in[15];
    const float* Wdst = (const float*)d_in[16]; const float* bdst = (const float*)d_in[17];
    const float* attn = (const float*)d_in[18];
    const float* temb = (const float*)d_in[19]; const float* semb = (const float*)d_in[20];
    const float* Wg   = (const float*)d_in[21]; const float* bg   = (const float*)d_in[22];
    const float* W1c  = (const float*)d_in[23]; const float* b1c  = (const float*)d_in[24];
    const float* W2c  = (const float*)d_in[25]; const float* b2c  = (const float*)d_in[26];
    const float* Wout = (const float*)d_in[27]; const float* bout = (const float*)d_in[28];

    constexpr int NC = 50000, NG = 30000, ND = 10000, NP = 5000;
    constexpr int E0 = 500000, E1 = 500000, E2 = 250000, E3 = 250000;
    constexpr int GCAP = 80000;

    char* ws = (char*)d_ws;
    float* gt   = (float*)ws;              // [64][128] f32 = 32768 B
    int*   csum = (int*)(ws + 32768);      // chunk sums for scan (<=49 ints)
    char*  A    = ws + 65536;              // stage arena (<= 63,360,000 B)

    float* out = (float*)d_out;
    float* out_chem = out;
    float* out_gene = out + (size_t)NC * 128;
    float* out_dis  = out + (size_t)(NC + NG) * 128;
    float* out_path = out + (size_t)(NC + NG + ND) * 128;

    gtbl_k<<<32, 256, 0, stream>>>(temb, semb, Wg, bg, gt);

    // ---------- STAGE A: chemical output (t1: gene -> chemical) ----------
    {
        float* hs1  = (float*)(A);                 // 15,360,000
        float* ad1  = (float*)(A + 15360000);      //    800,000
        int*   deg  = (int*)  (A + 16160000);      //    200,000
        int*   sts  = (int*)  (A + 16360000);      //    200,000
        int*   cur  = (int*)  (A + 16560000);      //    200,000
        int*   perm = (int*)  (A + 16760000);      //  2,000,000
        float* agg1 = (float*)(A + 18760000);      // 25,600,000 (ends 44,360,000)
        int nch = (NC + 1023) / 1024;
        zero_k<<<(NC + 255) / 256, 256, 0, stream>>>((float*)deg, NC);
        hist_k<<<(E1 + 255) / 256, 256, 0, stream>>>(dst1, deg, E1, NC);
        scan1_k<<<nch, 256, 0, stream>>>(deg, csum, NC);
        scan2_k<<<1, 64, 0, stream>>>(csum, nch);
        scan3_k<<<nch, 256, 0, stream>>>(deg, csum, sts, cur, NC);
        scatter_k<<<(E1 + 255) / 256, 256, 0, stream>>>(dst1, cur, perm, E1, NC);
        hsrow4_k<<<(NG + 15) / 16, 256, 0, stream>>>(x_gene, Wsrc + 1 * 16384, bsrc + 1 * 128, hs1, NG);
        adirect4_k<<<(NC + 15) / 16, 256, 0, stream>>>(x_chem, Wdst + 1 * 16384, bdst + 1 * 128, attn + 1 * 128, ad1, NC);
        agg_k<0><<<2048, 256, 0, stream>>>(hs1, ad1, src1, perm, sts, deg, attn + 1 * 128,
                                           nullptr, nullptr, nullptr, agg1, 0, NC, NG);
        outrow4_k<1><<<(NC + 15) / 16, 256, 0, stream>>>(agg1, nullptr,
                                                         Wout + 0 * 16384, bout + 0 * 128, out_chem, NC);
    }

    // ---------- STAGE B: pathway output (t2: chemical -> pathway) ----------
    {
        float* hs2  = (float*)(A);                 // 25,600,000
        float* ad2  = (float*)(A + 25600000);      //     80,000
        int*   deg  = (int*)  (A + 25680000);      //     20,000
        int*   sts  = (int*)  (A + 25700000);      //     20,000
        int*   cur  = (int*)  (A + 25720000);      //     20,000
        int*   perm = (int*)  (A + 25740000);      //  1,000,000
        float* agg2 = (float*)(A + 26740000);      //  2,560,000 (ends 29,300,000)
        u16*   gatep = (u16*) (A + 29300000);      // 20,480,000 (ends 49,780,000)
        int nch = (NP + 1023) / 1024;
        zero_k<<<(NP + 255) / 256, 256, 0, stream>>>((float*)deg, NP);
        hist_k<<<(E2 + 255) / 256, 256, 0, stream>>>(dst2, deg, E2, NP);
        scan1_k<<<nch, 256, 0, stream>>>(deg, csum, NP);
        scan2_k<<<1, 64, 0, stream>>>(csum, nch);
        scan3_k<<<nch, 256, 0, stream>>>(deg, csum, sts, cur, NP);
        scatter_k<<<(E2 + 255) / 256, 256, 0, stream>>>(dst2, cur, perm, E2, NP);
        hsrow4_k<<<(NC + 15) / 16, 256, 0, stream>>>(x_chem, Wsrc + 2 * 16384, bsrc + 2 * 128, hs2, NC);
        adirect4_k<<<(NP + 15) / 16, 256, 0, stream>>>(x_path, Wdst + 2 * 16384, bdst + 2 * 128, attn + 2 * 128, ad2, NP);
        for (int ck = 0; ck < 4; ck++) {
            int j0 = ck * 1250, j1 = j0 + 1250;
            gate_k<<<1024, 256, 0, stream>>>(cp, W1c, b1c, W2c, b2c, perm, sts, gatep,
                                             j0, j1, NP, E2, GCAP);
            agg_k<3><<<313, 256, 0, stream>>>(hs2, ad2, src2, perm, sts, deg, attn + 2 * 128,
                                              nullptr, nullptr, gatep, agg2, j0, j1, NC);
        }
        outrow4_k<1><<<(NP + 15) / 16, 256, 0, stream>>>(agg2, nullptr,
                                                         Wout + 3 * 16384, bout + 3 * 128, out_path, NP);
    }

    // ---------- STAGE C: gene output (t0 + t3, sequential buffer reuse) -----
    {
        float* agg0 = (float*)(A + 32000000);      // 15,360,000 (ends 47,360,000)
        float* agg3 = (float*)(A + 47360000);      // 15,360,000 (ends 62,720,000)
        float* ad0  = (float*)(A + 25600000);      //    480,000
        float* ad3  = (float*)(A + 28440000);      //    480,000 (survives phase 2)
        int*   deg  = (int*)  (A + 26080000);      //    120,000
        int*   sts  = (int*)  (A + 26200000);      //    120,000
        int*   cur  = (int*)  (A + 26320000);      //    120,000
        int*   perm = (int*)  (A + 26440000);      //  2,000,000 (ends 28,440,000)
        int nch = (NG + 1023) / 1024;

        // phase 1: t0 chemical -> gene (categorical gate)
        float* hs0 = (float*)(A);                  // 25,600,000
        zero_k<<<(NG + 255) / 256, 256, 0, stream>>>((float*)deg, NG);
        hist_k<<<(E0 + 255) / 256, 256, 0, stream>>>(dst0, deg, E0, NG);
        scan1_k<<<nch, 256, 0, stream>>>(deg, csum, NG);
        scan2_k<<<1, 64, 0, stream>>>(csum, nch);
        scan3_k<<<nch, 256, 0, stream>>>(deg, csum, sts, cur, NG);
        scatter_k<<<(E0 + 255) / 256, 256, 0, stream>>>(dst0, cur, perm, E0, NG);
        hsrow4_k<<<(NC + 15) / 16, 256, 0, stream>>>(x_chem, Wsrc + 0 * 16384, bsrc + 0 * 128, hs0, NC);
        adirect4_k<<<(NG + 15) / 16, 256, 0, stream>>>(x_gene, Wdst + 0 * 16384, bdst + 0 * 128, attn + 0 * 128, ad0, NG);
        adirect4_k<<<(NG + 15) / 16, 256, 0, stream>>>(x_gene, Wdst + 3 * 16384, bdst + 3 * 128, attn + 3 * 128, ad3, NG);
        agg_k<1><<<2048, 256, 0, stream>>>(hs0, ad0, src0, perm, sts, deg, attn + 0 * 128,
                                           cg, gt, nullptr, agg0, 0, NG, NC);

        // phase 2: t3 disease -> gene (plain), reusing hs/CSR buffers
        float* hs3 = (float*)(A);                  //  5,120,000
        zero_k<<<(NG + 255) / 256, 256, 0, stream>>>((float*)deg, NG);
        hist_k<<<(E3 + 255) / 256, 256, 0, stream>>>(dst3, deg, E3, NG);
        scan1_k<<<nch, 256, 0, stream>>>(deg, csum, NG);
        scan2_k<<<1, 64, 0, stream>>>(csum, nch);
        scan3_k<<<nch, 256, 0, stream>>>(deg, csum, sts, cur, NG);
        scatter_k<<<(E3 + 255) / 256, 256, 0, stream>>>(dst3, cur, perm, E3, NG);
        hsrow4_k<<<(ND + 15) / 16, 256, 0, stream>>>(x_dis, Wsrc + 3 * 16384, bsrc + 3 * 128, hs3, ND);
        agg_k<0><<<2048, 256, 0, stream>>>(hs3, ad3, src3, perm, sts, deg, attn + 3 * 128,
                                           nullptr, nullptr, nullptr, agg3, 0, NG, ND);
        outrow4_k<2><<<(NG + 15) / 16, 256, 0, stream>>>(agg0, agg3,
                                                         Wout + 1 * 16384, bout + 1 * 128, out_gene, NG);
    }

    // ---------- STAGE D: disease output (no incoming edges: bias only) ------
    outrow4_k<0><<<(ND + 15) / 16, 256, 0, stream>>>(nullptr, nullptr,
                                                     Wout + 2 * 16384, bout + 2 * 128, out_dis, ND);
}